// Round 2
// baseline (694.431 us; speedup 1.0000x reference)
//
#include <hip/hip_runtime.h>

#define LOG2E 1.44269504088896340736f
#define QSCALE 0.18033688011112042f  // 0.125 * LOG2E

typedef __attribute__((ext_vector_type(8))) short bf16x8;
typedef __attribute__((ext_vector_type(4))) float f32x4;

__device__ __forceinline__ unsigned short f2b(float f) {
  union { float f; unsigned int u; } x; x.f = f;
  return (unsigned short)((x.u + 0x8000u) >> 16);
}

// pack two fp32 -> two bf16 in 3 VALU ops
__device__ __forceinline__ unsigned int pk_bf16(float a, float b) {
  union { float f; unsigned int u; } xa, xb; xa.f = a; xb.f = b;
  return __builtin_amdgcn_perm(xb.u + 0x8000u, xa.u + 0x8000u, 0x07060302);
}

__device__ __forceinline__ void gld_lds16(const void* g, void* l) {
  __builtin_amdgcn_global_load_lds((const __attribute__((address_space(1))) void*)g,
                                   (__attribute__((address_space(3))) void*)l,
                                   16, 0, 0);
}

// raw workgroup barrier (NO implicit vmcnt drain, unlike __syncthreads)
__device__ __forceinline__ void wgbar() {
  asm volatile("" ::: "memory");
  __builtin_amdgcn_s_barrier();
  asm volatile("" ::: "memory");
}
#define SWAIT(s) asm volatile("s_waitcnt " s ::: "memory")

// ---------------- fused cast x,y fp32 -> bf16 ----------------
__global__ __launch_bounds__(256) void cast_xy(const float* __restrict__ x,
                                               const float* __restrict__ y,
                                               unsigned short* __restrict__ xb,
                                               unsigned short* __restrict__ yb) {
  int i = blockIdx.x * 256 + threadIdx.x;
  const float* in = x; unsigned short* out = xb;
  if (i >= 2097152) { in = y; out = yb; i -= 2097152; }
  float4 v = ((const float4*)in)[i];
  uint2 o;
  o.x = pk_bf16(v.x, v.y);
  o.y = pk_bf16(v.z, v.w);
  ((uint2*)out)[i] = o;
}

// ---------------- mask pre-scale: out = mask * log2(e), fp32 ----------------
__global__ __launch_bounds__(256) void scale_mask(const float* __restrict__ in,
                                                  float* __restrict__ out) {
  int i = blockIdx.x * 256 + threadIdx.x;
  f32x4 v = ((const f32x4*)in)[i];
  ((f32x4*)out)[i] = v * LOG2E;
}

// ---------------- fused transpose+cast of Wkv, Wq, Wo ----------------
__global__ __launch_bounds__(256) void transpose_cast_all(
    const float* __restrict__ Wkv, const float* __restrict__ Wq,
    const float* __restrict__ Wo, unsigned short* __restrict__ wkvt,
    unsigned short* __restrict__ wqt, unsigned short* __restrict__ wot) {
  __shared__ float t[32][33];
  int tb = blockIdx.x;
  const float* W; unsigned short* Wt; int N;
  if (tb < 2048)      { W = Wkv; Wt = wkvt; N = 2048; }
  else if (tb < 3072) { W = Wq;  Wt = wqt;  N = 1024; tb -= 2048; }
  else                { W = Wo;  Wt = wot;  N = 1024; tb -= 3072; }
  const int K = 1024;
  int tilesN = N >> 5;
  int nb = (tb % tilesN) * 32, kb = (tb / tilesN) * 32;
  int j = threadIdx.x & 31, i0 = threadIdx.x >> 5;
  #pragma unroll
  for (int p = 0; p < 4; ++p) {
    int i = i0 + p * 8;
    t[i][j] = W[(size_t)(kb + i) * N + nb + j];
  }
  __syncthreads();
  #pragma unroll
  for (int p = 0; p < 4; ++p) {
    int i = i0 + p * 8;
    Wt[(size_t)(nb + i) * K + kb + j] = f2b(t[j][i]);
  }
}

// ---------------- GEMM: C(MxN) = A(MxK) @ Bt(NxK)^T + bias ----------------
// XOR-granule-swizzled LDS (conflict-free b128 fragment reads).
// MODE 0: fp32 C out. MODE 1: kv -> K[b,h,s,64] + Vt[b,h,64,s]. MODE 2: q -> Q * QSCALE.
template <int MODE>
__global__ __launch_bounds__(256)
void gemm128(const unsigned short* __restrict__ A,
             const unsigned short* __restrict__ Bt,
             const float* __restrict__ bias,
             void* __restrict__ out0, void* __restrict__ out1,
             int M, int N, int K) {
  __shared__ __align__(16) unsigned short As[128 * 64];
  __shared__ __align__(16) unsigned short Bs[128 * 64];
  const int tid = threadIdx.x;
  const int bn = blockIdx.x, bm = blockIdx.y;
  const int wave = tid >> 6, lane = tid & 63;
  const int wm = (wave >> 1) * 64, wn = (wave & 1) * 64;
  const int lrow = lane & 15, quad = lane >> 4;
  const int sw = lrow & 7;  // fragment-read granule swizzle

  f32x4 acc[4][4];
  #pragma unroll
  for (int i = 0; i < 4; ++i)
    #pragma unroll
    for (int j = 0; j < 4; ++j)
      #pragma unroll
      for (int r = 0; r < 4; ++r) acc[i][j][r] = 0.f;

  const unsigned short* Ab = A + (size_t)(bm * 128) * K;
  const unsigned short* Bb = Bt + (size_t)(bn * 128) * K;

  for (int k0 = 0; k0 < K; k0 += 64) {
    #pragma unroll
    for (int i = 0; i < 4; ++i) {
      int e = i * 256 + tid;
      int row = e >> 3, gs = (e & 7) ^ (row & 7);
      gld_lds16(Ab + (size_t)row * K + k0 + gs * 8, &As[e * 8]);
    }
    #pragma unroll
    for (int i = 0; i < 4; ++i) {
      int e = i * 256 + tid;
      int row = e >> 3, gs = (e & 7) ^ (row & 7);
      gld_lds16(Bb + (size_t)row * K + k0 + gs * 8, &Bs[e * 8]);
    }
    __builtin_amdgcn_s_waitcnt(0);
    __syncthreads();
    #pragma unroll
    for (int ks = 0; ks < 2; ++ks) {
      bf16x8 af[4], bf[4];
      const int g = ((ks * 4 + quad) ^ sw) * 8;
      #pragma unroll
      for (int i = 0; i < 4; ++i)
        af[i] = *(const bf16x8*)&As[(wm + i * 16 + lrow) * 64 + g];
      #pragma unroll
      for (int j = 0; j < 4; ++j)
        bf[j] = *(const bf16x8*)&Bs[(wn + j * 16 + lrow) * 64 + g];
      #pragma unroll
      for (int i = 0; i < 4; ++i)
        #pragma unroll
        for (int j = 0; j < 4; ++j)
          acc[i][j] = __builtin_amdgcn_mfma_f32_16x16x32_bf16(af[i], bf[j], acc[i][j], 0, 0, 0);
    }
    __syncthreads();
  }

  const int col0 = bn * 128 + wn;
  #pragma unroll
  for (int i = 0; i < 4; ++i) {
    const int row0 = bm * 128 + wm + i * 16 + quad * 4;
    const int b = row0 >> 11, s0 = row0 & 2047;
    #pragma unroll
    for (int j = 0; j < 4; ++j) {
      const int cc = j * 16 + lrow;
      const float bv = bias[col0 + cc];
      float v0 = acc[i][j][0] + bv, v1 = acc[i][j][1] + bv;
      float v2 = acc[i][j][2] + bv, v3 = acc[i][j][3] + bv;
      if (MODE == 0) {
        float* C = (float*)out0;
        size_t off = (size_t)row0 * N + col0 + cc;
        C[off] = v0; C[off + N] = v1; C[off + 2 * N] = v2; C[off + 3 * N] = v3;
      } else if (MODE == 1) {
        const int h = col0 >> 7;
        if ((col0 & 64) == 0) {  // K half: K[b,h,s,64]
          unsigned short* Kb = (unsigned short*)out0;
          size_t base = ((size_t)(b * 16 + h) * 2048 + s0) * 64 + cc;
          Kb[base] = f2b(v0); Kb[base + 64] = f2b(v1);
          Kb[base + 128] = f2b(v2); Kb[base + 192] = f2b(v3);
        } else {                 // V half: Vt[b,h,64,s]
          unsigned short* Vt = (unsigned short*)out1;
          size_t base = ((size_t)(b * 16 + h) * 64 + cc) * 2048 + s0;
          uint2 p; p.x = pk_bf16(v0, v1); p.y = pk_bf16(v2, v3);
          *(uint2*)&Vt[base] = p;
        }
      } else {  // MODE 2: Q[b,h,s,64] pre-scaled
        v0 *= QSCALE; v1 *= QSCALE; v2 *= QSCALE; v3 *= QSCALE;
        const int h = col0 >> 6;
        unsigned short* Qb = (unsigned short*)out0;
        size_t base = ((size_t)(b * 16 + h) * 2048 + s0) * 64 + cc;
        Qb[base] = f2b(v0); Qb[base + 64] = f2b(v1);
        Qb[base + 128] = f2b(v2); Qb[base + 192] = f2b(v3);
      }
    }
  }
}

// ---------------- flash attention v6: 2 barriers/tile, reg-mask prefetch ----
// grid 1024; 2 qt per XCD. 4 waves x 32 q-cols. K dbuf; V single buffer issued
// post-B2; mask rows ik0,1 prefetched 1 tile ahead into regs (double-buffered),
// ik2,3 loaded at tile top (covered by ik0,1 MFMAs). Single vmcnt(0) at top
// retires only >=0.7-tile-old loads; B1 publishes K(t)+V(t). P roundtrip stays
// wave-private (lgkmcnt only). LDS = 40960 B -> 4 blocks/CU.
__global__ __launch_bounds__(256, 4)
void attn(const unsigned short* __restrict__ Qbuf,
          const unsigned short* __restrict__ Kbuf,
          const unsigned short* __restrict__ Vtbuf,
          const float* __restrict__ masks,   // mask * log2e, fp32
          unsigned short* __restrict__ vals) {
  const int blk = blockIdx.x;
  const int xcd = blk & 7, slot = blk >> 3;       // slot 0..127
  const int qt = xcd * 2 + (slot >> 6);           // 2 qt values per XCD
  const int hb = slot & 63;
  const int b = hb >> 4, h = hb & 15;
  const int tid = threadIdx.x, lane = tid & 63, w = tid >> 6;
  const int lrow = lane & 15, quad = lane >> 4;
  const int sw = lrow & 7;

  __shared__ __align__(16) unsigned short Ks[2][64 * 64];  // [key][d] swizzled, dbuf
  __shared__ __align__(16) unsigned short Vs[64 * 64];     // [d][key] swizzled
  __shared__ __align__(16) unsigned short Ps[128 * 64];    // Q staging, then P (swizzled)

  const unsigned short* qp = Qbuf + ((size_t)(b * 16 + h) * 2048 + qt * 128) * 64;
  const unsigned short* kp = Kbuf + (size_t)(b * 16 + h) * 2048 * 64;
  const unsigned short* vp = Vtbuf + (size_t)(b * 16 + h) * 64 * 2048;
  const float* mp = masks + (size_t)(qt * 128 + w * 32) * 2048;

  // ---- prologue: stage Q (swizzled), K tile 0, V tile 0, mask(0) ik0,1 ----
  #pragma unroll
  for (int i = 0; i < 4; ++i) {
    int e = i * 256 + tid;
    int row = e >> 3, gs = (e & 7) ^ (row & 7);
    gld_lds16(qp + (size_t)row * 64 + gs * 8, &Ps[e * 8]);
  }
  #pragma unroll
  for (int i = 0; i < 2; ++i) {  // K tile 0
    int e = i * 256 + tid;
    int row = e >> 3, gs = (e & 7) ^ (row & 7);
    gld_lds16(kp + (size_t)row * 64 + gs * 8, &Ks[0][e * 8]);
  }
  #pragma unroll
  for (int i = 0; i < 2; ++i) {  // V^T tile 0
    int e = i * 256 + tid;
    int row = e >> 3, gs = (e & 7) ^ (row & 7);
    gld_lds16(vp + (size_t)row * 2048 + gs * 8, &Vs[e * 8]);
  }
  f32x4 zm0[2][2], zm1[2][2];  // mask frags ik=0,1 (double-buffered across tiles)
  #pragma unroll
  for (int iq = 0; iq < 2; ++iq) {
    const float* mrow = mp + (size_t)(iq * 16 + lrow) * 2048 + quad * 4;
    zm0[0][iq] = *(const f32x4*)(mrow);
    zm0[1][iq] = *(const f32x4*)(mrow + 16);
  }
  SWAIT("vmcnt(0)");
  wgbar();  // publish Q, K0, V0

  bf16x8 qf[2][2];  // [iq][ks]  B-operand: n=q, k=d
  #pragma unroll
  for (int iq = 0; iq < 2; ++iq)
    #pragma unroll
    for (int ks = 0; ks < 2; ++ks)
      qf[iq][ks] = *(const bf16x8*)&Ps[(w * 32 + iq * 16 + lrow) * 64 + ((ks * 4 + quad) ^ sw) * 8];
  // Ps reuse for P is wave-private (wave w reads/writes rows [w*32, w*32+32) only).

  f32x4 o_acc[4][2];  // O^T: d = id*16+quad*4+r, q = iq*16+lrow
  #pragma unroll
  for (int id = 0; id < 4; ++id)
    #pragma unroll
    for (int iq = 0; iq < 2; ++iq)
      #pragma unroll
      for (int r = 0; r < 4; ++r) o_acc[id][iq][r] = 0.f;
  float lsum[2] = {0.f, 0.f};

  // invariant at tile top: outstanding vmem = K(t):2 + V(t):2 + mask(t)ik01:4,
  // all issued >=0.7 tile ago -> vmcnt(0) is non-blocking.
  auto tile_body = [&](int t, f32x4 (&zc01)[2][2], f32x4 (&zn01)[2][2]) {
    unsigned short* Kc = &Ks[t & 1][0];
    unsigned short* Kn = &Ks[(t + 1) & 1][0];
    const int ktn = (t + 1) & 31;  // wrapped dummy prefetch at t=31

    SWAIT("vmcnt(0)");
    wgbar();  // B1: K(t), V(t) published; Ks[(t+1)&1] reader-free

    #pragma unroll
    for (int i = 0; i < 2; ++i) {  // issue K(t+1)
      int e = i * 256 + tid;
      int row = e >> 3, gs = (e & 7) ^ (row & 7);
      gld_lds16(kp + (size_t)(ktn * 64 + row) * 64 + gs * 8, &Kn[e * 8]);
    }
    // issue mask(t+1) ik0,1 (reg prefetch) and mask(t) ik2,3 (used ~200cy later)
    f32x4 zc23[2][2];
    #pragma unroll
    for (int iq = 0; iq < 2; ++iq) {
      const float* mrow = mp + (size_t)(iq * 16 + lrow) * 2048 + quad * 4;
      zn01[0][iq] = *(const f32x4*)(mrow + ktn * 64);
      zn01[1][iq] = *(const f32x4*)(mrow + ktn * 64 + 16);
      zc23[0][iq] = *(const f32x4*)(mrow + t * 64 + 32);
      zc23[1][iq] = *(const f32x4*)(mrow + t * 64 + 48);
    }

    // QK + softmax, ik-major (per-ik kf reads keep VGPR low; softmax VALU of
    // ik overlaps MFMA of ik+1)
    #pragma unroll
    for (int ik = 0; ik < 4; ++ik) {
      const int krow = (ik * 16 + lrow) * 64;
      bf16x8 kf0 = *(const bf16x8*)&Kc[krow + ((quad ^ sw) * 8)];
      bf16x8 kf1 = *(const bf16x8*)&Kc[krow + (((4 + quad) ^ sw) * 8)];
      #pragma unroll
      for (int iq = 0; iq < 2; ++iq) {
        f32x4 zz = (ik < 2) ? zc01[ik][iq] : zc23[ik - 2][iq];
        zz = __builtin_amdgcn_mfma_f32_16x16x32_bf16(kf0, qf[iq][0], zz, 0, 0, 0);
        zz = __builtin_amdgcn_mfma_f32_16x16x32_bf16(kf1, qf[iq][1], zz, 0, 0, 0);
        float e0 = exp2f(zz[0]), e1 = exp2f(zz[1]);
        float e2 = exp2f(zz[2]), e3 = exp2f(zz[3]);
        lsum[iq] += (e0 + e1) + (e2 + e3);
        uint2 p;
        p.x = pk_bf16(e0, e1);
        p.y = pk_bf16(e2, e3);
        // P[q][k], k0 = ik*16+quad*4: granule (k0>>3)^sw, 8B half (quad&1)
        *(uint2*)&Ps[(w * 32 + iq * 16 + lrow) * 64 +
                     ((ik * 2 + (quad >> 1)) ^ sw) * 8 + (quad & 1) * 4] = p;
      }
    }
    SWAIT("lgkmcnt(0)");  // own Ps writes -> own reads (wave-private, no barrier)

    // O^T += V^T P^T
    #pragma unroll
    for (int ks = 0; ks < 2; ++ks) {
      bf16x8 vf[4], pf[2];
      const int g = ((ks * 4 + quad) ^ sw) * 8;
      #pragma unroll
      for (int id = 0; id < 4; ++id)
        vf[id] = *(const bf16x8*)&Vs[(id * 16 + lrow) * 64 + g];
      #pragma unroll
      for (int iq = 0; iq < 2; ++iq)
        pf[iq] = *(const bf16x8*)&Ps[(w * 32 + iq * 16 + lrow) * 64 + g];
      #pragma unroll
      for (int id = 0; id < 4; ++id)
        #pragma unroll
        for (int iq = 0; iq < 2; ++iq)
          o_acc[id][iq] = __builtin_amdgcn_mfma_f32_16x16x32_bf16(vf[id], pf[iq], o_acc[id][iq], 0, 0, 0);
    }

    wgbar();  // B2: all waves done reading Vs

    #pragma unroll
    for (int i = 0; i < 2; ++i) {  // issue V(t+1) (consumed after next QK+softmax)
      int e = i * 256 + tid;
      int row = e >> 3, gs = (e & 7) ^ (row & 7);
      gld_lds16(vp + (size_t)row * 2048 + ktn * 64 + gs * 8, &Vs[e * 8]);
    }
  };

  for (int t = 0; t < 32; t += 2) {
    tile_body(t, zm0, zm1);
    tile_body(t + 1, zm1, zm0);
  }

  // normalize + store O^T
  unsigned short* ob = vals + (size_t)(b * 2048 + qt * 128 + w * 32) * 1024 + h * 64;
  #pragma unroll
  for (int iq = 0; iq < 2; ++iq) {
    float s = lsum[iq];
    s += __shfl_xor(s, 16);
    s += __shfl_xor(s, 32);
    float inv = 1.f / s;
    #pragma unroll
    for (int id = 0; id < 4; ++id) {
      uint2 p;
      p.x = pk_bf16(o_acc[id][iq][0] * inv, o_acc[id][iq][1] * inv);
      p.y = pk_bf16(o_acc[id][iq][2] * inv, o_acc[id][iq][3] * inv);
      *(uint2*)&ob[(size_t)(iq * 16 + lrow) * 1024 + id * 16 + quad * 4] = p;
    }
  }
}

extern "C" void kernel_launch(void* const* d_in, const int* in_sizes, int n_in,
                              void* d_out, int out_size, void* d_ws, size_t ws_size,
                              hipStream_t stream) {
  const float* x    = (const float*)d_in[0];
  const float* y    = (const float*)d_in[1];
  const float* mask = (const float*)d_in[2];
  const float* Wkv  = (const float*)d_in[3];
  const float* bkv  = (const float*)d_in[4];
  const float* Wq   = (const float*)d_in[5];
  const float* bq   = (const float*)d_in[6];
  const float* Wo   = (const float*)d_in[7];
  const float* bo   = (const float*)d_in[8];

  char* ws = (char*)d_ws;
  unsigned short* xb    = (unsigned short*)(ws + ((size_t)0 << 20));
  unsigned short* yb    = (unsigned short*)(ws + ((size_t)16 << 20));
  unsigned short* wkvt  = (unsigned short*)(ws + ((size_t)32 << 20));
  unsigned short* wqt   = (unsigned short*)(ws + ((size_t)36 << 20));
  unsigned short* wot   = (unsigned short*)(ws + ((size_t)38 << 20));
  unsigned short* kbuf  = (unsigned short*)(ws + ((size_t)40 << 20));
  unsigned short* vtbuf = (unsigned short*)(ws + ((size_t)56 << 20));
  unsigned short* qbuf  = (unsigned short*)(ws + ((size_t)72 << 20));
  unsigned short* valsb = (unsigned short*)(ws + ((size_t)88 << 20));
  float*          masks = (float*)        (ws + ((size_t)108 << 20));

  cast_xy<<<16384, 256, 0, stream>>>(x, y, xb, yb);
  scale_mask<<<4096, 256, 0, stream>>>(mask, masks);
  transpose_cast_all<<<4096, 256, 0, stream>>>(Wkv, Wq, Wo, wkvt, wqt, wot);

  // kv = x @ Wkv + bkv -> K[b,h,s,64], Vt[b,h,64,s]
  gemm128<1><<<dim3(16, 64), 256, 0, stream>>>(xb, wkvt, bkv, kbuf, vtbuf, 8192, 2048, 1024);
  // q = y @ Wq + bq -> Q[b,h,s,64] (pre-scaled)
  gemm128<2><<<dim3(8, 64), 256, 0, stream>>>(yb, wqt, bq, qbuf, nullptr, 8192, 1024, 1024);
  // attention -> vals [b,s,1024] bf16
  attn<<<1024, 256, 0, stream>>>(qbuf, kbuf, vtbuf, masks, valsb);
  // out = vals @ Wo + bo (fp32)
  gemm128<0><<<dim3(8, 64), 256, 0, stream>>>(valsb, wot, bo, (float*)d_out, nullptr, 8192, 1024, 1024);
}

// Round 3
// 456.308 us; speedup vs baseline: 1.5218x; 1.5218x over previous
//
#include <hip/hip_runtime.h>

#define LOG2E 1.44269504088896340736f
#define QSCALE 0.18033688011112042f  // 0.125 * LOG2E

typedef __attribute__((ext_vector_type(8))) short bf16x8;
typedef __attribute__((ext_vector_type(4))) float f32x4;

__device__ __forceinline__ unsigned short f2b(float f) {
  union { float f; unsigned int u; } x; x.f = f;
  return (unsigned short)((x.u + 0x8000u) >> 16);
}

// pack two fp32 -> two bf16 in 3 VALU ops
__device__ __forceinline__ unsigned int pk_bf16(float a, float b) {
  union { float f; unsigned int u; } xa, xb; xa.f = a; xb.f = b;
  return __builtin_amdgcn_perm(xb.u + 0x8000u, xa.u + 0x8000u, 0x07060302);
}

__device__ __forceinline__ void gld_lds16(const void* g, void* l) {
  __builtin_amdgcn_global_load_lds((const __attribute__((address_space(1))) void*)g,
                                   (__attribute__((address_space(3))) void*)l,
                                   16, 0, 0);
}

// raw workgroup barrier (NO implicit vmcnt drain, unlike __syncthreads)
__device__ __forceinline__ void wgbar() {
  asm volatile("" ::: "memory");
  __builtin_amdgcn_s_barrier();
  asm volatile("" ::: "memory");
}
#define SWAIT(s) asm volatile("s_waitcnt " s ::: "memory")

// ---------------- fused cast x,y fp32 -> bf16 ----------------
__global__ __launch_bounds__(256) void cast_xy(const float* __restrict__ x,
                                               const float* __restrict__ y,
                                               unsigned short* __restrict__ xb,
                                               unsigned short* __restrict__ yb) {
  int i = blockIdx.x * 256 + threadIdx.x;
  const float* in = x; unsigned short* out = xb;
  if (i >= 2097152) { in = y; out = yb; i -= 2097152; }
  float4 v = ((const float4*)in)[i];
  uint2 o;
  o.x = pk_bf16(v.x, v.y);
  o.y = pk_bf16(v.z, v.w);
  ((uint2*)out)[i] = o;
}

// ---------------- mask pre-scale: out = mask * log2(e), fp32 ----------------
__global__ __launch_bounds__(256) void scale_mask(const float* __restrict__ in,
                                                  float* __restrict__ out) {
  int i = blockIdx.x * 256 + threadIdx.x;
  f32x4 v = ((const f32x4*)in)[i];
  ((f32x4*)out)[i] = v * LOG2E;
}

// ---------------- fused transpose+cast of Wkv, Wq, Wo ----------------
__global__ __launch_bounds__(256) void transpose_cast_all(
    const float* __restrict__ Wkv, const float* __restrict__ Wq,
    const float* __restrict__ Wo, unsigned short* __restrict__ wkvt,
    unsigned short* __restrict__ wqt, unsigned short* __restrict__ wot) {
  __shared__ float t[32][33];
  int tb = blockIdx.x;
  const float* W; unsigned short* Wt; int N;
  if (tb < 2048)      { W = Wkv; Wt = wkvt; N = 2048; }
  else if (tb < 3072) { W = Wq;  Wt = wqt;  N = 1024; tb -= 2048; }
  else                { W = Wo;  Wt = wot;  N = 1024; tb -= 3072; }
  const int K = 1024;
  int tilesN = N >> 5;
  int nb = (tb % tilesN) * 32, kb = (tb / tilesN) * 32;
  int j = threadIdx.x & 31, i0 = threadIdx.x >> 5;
  #pragma unroll
  for (int p = 0; p < 4; ++p) {
    int i = i0 + p * 8;
    t[i][j] = W[(size_t)(kb + i) * N + nb + j];
  }
  __syncthreads();
  #pragma unroll
  for (int p = 0; p < 4; ++p) {
    int i = i0 + p * 8;
    Wt[(size_t)(nb + i) * K + kb + j] = f2b(t[j][i]);
  }
}

// ---------------- GEMM: C(MxN) = A(MxK) @ Bt(NxK)^T + bias ----------------
// XOR-granule-swizzled LDS (conflict-free b128 fragment reads).
// MODE 0: fp32 C out. MODE 1: kv -> K[b,h,s,64] + Vt[b,h,64,s]. MODE 2: q -> Q * QSCALE.
template <int MODE>
__global__ __launch_bounds__(256)
void gemm128(const unsigned short* __restrict__ A,
             const unsigned short* __restrict__ Bt,
             const float* __restrict__ bias,
             void* __restrict__ out0, void* __restrict__ out1,
             int M, int N, int K) {
  __shared__ __align__(16) unsigned short As[128 * 64];
  __shared__ __align__(16) unsigned short Bs[128 * 64];
  const int tid = threadIdx.x;
  const int bn = blockIdx.x, bm = blockIdx.y;
  const int wave = tid >> 6, lane = tid & 63;
  const int wm = (wave >> 1) * 64, wn = (wave & 1) * 64;
  const int lrow = lane & 15, quad = lane >> 4;
  const int sw = lrow & 7;  // fragment-read granule swizzle

  f32x4 acc[4][4];
  #pragma unroll
  for (int i = 0; i < 4; ++i)
    #pragma unroll
    for (int j = 0; j < 4; ++j)
      #pragma unroll
      for (int r = 0; r < 4; ++r) acc[i][j][r] = 0.f;

  const unsigned short* Ab = A + (size_t)(bm * 128) * K;
  const unsigned short* Bb = Bt + (size_t)(bn * 128) * K;

  for (int k0 = 0; k0 < K; k0 += 64) {
    #pragma unroll
    for (int i = 0; i < 4; ++i) {
      int e = i * 256 + tid;
      int row = e >> 3, gs = (e & 7) ^ (row & 7);
      gld_lds16(Ab + (size_t)row * K + k0 + gs * 8, &As[e * 8]);
    }
    #pragma unroll
    for (int i = 0; i < 4; ++i) {
      int e = i * 256 + tid;
      int row = e >> 3, gs = (e & 7) ^ (row & 7);
      gld_lds16(Bb + (size_t)row * K + k0 + gs * 8, &Bs[e * 8]);
    }
    __builtin_amdgcn_s_waitcnt(0);
    __syncthreads();
    #pragma unroll
    for (int ks = 0; ks < 2; ++ks) {
      bf16x8 af[4], bf[4];
      const int g = ((ks * 4 + quad) ^ sw) * 8;
      #pragma unroll
      for (int i = 0; i < 4; ++i)
        af[i] = *(const bf16x8*)&As[(wm + i * 16 + lrow) * 64 + g];
      #pragma unroll
      for (int j = 0; j < 4; ++j)
        bf[j] = *(const bf16x8*)&Bs[(wn + j * 16 + lrow) * 64 + g];
      #pragma unroll
      for (int i = 0; i < 4; ++i)
        #pragma unroll
        for (int j = 0; j < 4; ++j)
          acc[i][j] = __builtin_amdgcn_mfma_f32_16x16x32_bf16(af[i], bf[j], acc[i][j], 0, 0, 0);
    }
    __syncthreads();
  }

  const int col0 = bn * 128 + wn;
  #pragma unroll
  for (int i = 0; i < 4; ++i) {
    const int row0 = bm * 128 + wm + i * 16 + quad * 4;
    const int b = row0 >> 11, s0 = row0 & 2047;
    #pragma unroll
    for (int j = 0; j < 4; ++j) {
      const int cc = j * 16 + lrow;
      const float bv = bias[col0 + cc];
      float v0 = acc[i][j][0] + bv, v1 = acc[i][j][1] + bv;
      float v2 = acc[i][j][2] + bv, v3 = acc[i][j][3] + bv;
      if (MODE == 0) {
        float* C = (float*)out0;
        size_t off = (size_t)row0 * N + col0 + cc;
        C[off] = v0; C[off + N] = v1; C[off + 2 * N] = v2; C[off + 3 * N] = v3;
      } else if (MODE == 1) {
        const int h = col0 >> 7;
        if ((col0 & 64) == 0) {  // K half: K[b,h,s,64]
          unsigned short* Kb = (unsigned short*)out0;
          size_t base = ((size_t)(b * 16 + h) * 2048 + s0) * 64 + cc;
          Kb[base] = f2b(v0); Kb[base + 64] = f2b(v1);
          Kb[base + 128] = f2b(v2); Kb[base + 192] = f2b(v3);
        } else {                 // V half: Vt[b,h,64,s]
          unsigned short* Vt = (unsigned short*)out1;
          size_t base = ((size_t)(b * 16 + h) * 64 + cc) * 2048 + s0;
          uint2 p; p.x = pk_bf16(v0, v1); p.y = pk_bf16(v2, v3);
          *(uint2*)&Vt[base] = p;
        }
      } else {  // MODE 2: Q[b,h,s,64] pre-scaled
        v0 *= QSCALE; v1 *= QSCALE; v2 *= QSCALE; v3 *= QSCALE;
        const int h = col0 >> 6;
        unsigned short* Qb = (unsigned short*)out0;
        size_t base = ((size_t)(b * 16 + h) * 2048 + s0) * 64 + cc;
        Qb[base] = f2b(v0); Qb[base + 64] = f2b(v1);
        Qb[base + 128] = f2b(v2); Qb[base + 192] = f2b(v3);
      }
    }
  }
}

// ---------------- flash attention v7: 1 barrier/tile, full dbuf, macro body --
// grid 1024; 2 qt per XCD. 4 waves x 32 q-cols. K AND V double-buffered; all
// 4 mask rows reg-prefetched one tile ahead (ping-pong zm0/zm1). At tile top a
// single vmcnt(0) retires only full-tile-old loads (non-blocking) and ONE
// s_barrier publishes K(t)+V(t) and frees the alternate buffers. Tile body is
// a macro (round-2 lambda was outlined -> 1.6 GB scratch traffic).
// LDS = 49152 B -> 3 blocks/CU; launch_bounds(256,3) allows ~168 VGPR.

#define ATTN_TILE(t, ZC, ZN)                                                   \
  {                                                                            \
    unsigned short* Kc = &Ks[(t) & 1][0];                                      \
    unsigned short* Kn = &Ks[((t) + 1) & 1][0];                                \
    unsigned short* Vc = &Vs[(t) & 1][0];                                      \
    unsigned short* Vn = &Vs[((t) + 1) & 1][0];                                \
    const int ktn = ((t) + 1) & 31; /* wrapped dummy prefetch at t=31 */       \
    SWAIT("vmcnt(0)"); /* K(t),V(t),mask(t): all issued a full tile ago */     \
    wgbar();           /* publish K(t),V(t); alt buffers reader-free */        \
    _Pragma("unroll")                                                          \
    for (int i = 0; i < 2; ++i) { /* issue K(t+1) */                           \
      int e = i * 256 + tid;                                                   \
      int row = e >> 3, gs = (e & 7) ^ (row & 7);                              \
      gld_lds16(kp + (size_t)(ktn * 64 + row) * 64 + gs * 8, &Kn[e * 8]);      \
    }                                                                          \
    _Pragma("unroll")                                                          \
    for (int i = 0; i < 2; ++i) { /* issue V(t+1) */                           \
      int e = i * 256 + tid;                                                   \
      int row = e >> 3, gs = (e & 7) ^ (row & 7);                              \
      gld_lds16(vp + (size_t)row * 2048 + ktn * 64 + gs * 8, &Vn[e * 8]);      \
    }                                                                          \
    _Pragma("unroll")                                                          \
    for (int iq = 0; iq < 2; ++iq) { /* mask(t+1) -> regs */                   \
      const float* mrow =                                                      \
          mp + (size_t)(iq * 16 + lrow) * 2048 + quad * 4 + ktn * 64;          \
      ZN[0][iq] = *(const f32x4*)(mrow);                                       \
      ZN[1][iq] = *(const f32x4*)(mrow + 16);                                  \
      ZN[2][iq] = *(const f32x4*)(mrow + 32);                                  \
      ZN[3][iq] = *(const f32x4*)(mrow + 48);                                  \
    }                                                                          \
    _Pragma("unroll")                                                          \
    for (int ik = 0; ik < 4; ++ik) { /* QK + softmax, ik-major */              \
      const int krow = (ik * 16 + lrow) * 64;                                  \
      bf16x8 kf0 = *(const bf16x8*)&Kc[krow + ((quad ^ sw) * 8)];              \
      bf16x8 kf1 = *(const bf16x8*)&Kc[krow + (((4 + quad) ^ sw) * 8)];        \
      _Pragma("unroll")                                                        \
      for (int iq = 0; iq < 2; ++iq) {                                         \
        f32x4 zz = ZC[ik][iq];                                                 \
        zz = __builtin_amdgcn_mfma_f32_16x16x32_bf16(kf0, qf[iq][0], zz, 0, 0, 0); \
        zz = __builtin_amdgcn_mfma_f32_16x16x32_bf16(kf1, qf[iq][1], zz, 0, 0, 0); \
        float e0 = exp2f(zz[0]), e1 = exp2f(zz[1]);                            \
        float e2 = exp2f(zz[2]), e3 = exp2f(zz[3]);                            \
        lsum[iq] += (e0 + e1) + (e2 + e3);                                     \
        uint2 p;                                                               \
        p.x = pk_bf16(e0, e1);                                                 \
        p.y = pk_bf16(e2, e3);                                                 \
        *(uint2*)&Ps[(w * 32 + iq * 16 + lrow) * 64 +                          \
                     ((ik * 2 + (quad >> 1)) ^ sw) * 8 + (quad & 1) * 4] = p;  \
      }                                                                        \
    }                                                                          \
    SWAIT("lgkmcnt(0)"); /* own wave-private Ps writes -> own reads */         \
    _Pragma("unroll")                                                          \
    for (int ks = 0; ks < 2; ++ks) { /* O^T += V^T P^T */                      \
      bf16x8 vf[4], pf[2];                                                     \
      const int g = ((ks * 4 + quad) ^ sw) * 8;                                \
      _Pragma("unroll")                                                        \
      for (int id = 0; id < 4; ++id)                                           \
        vf[id] = *(const bf16x8*)&Vc[(id * 16 + lrow) * 64 + g];               \
      _Pragma("unroll")                                                        \
      for (int iq = 0; iq < 2; ++iq)                                           \
        pf[iq] = *(const bf16x8*)&Ps[(w * 32 + iq * 16 + lrow) * 64 + g];      \
      _Pragma("unroll")                                                        \
      for (int id = 0; id < 4; ++id)                                           \
        _Pragma("unroll")                                                      \
        for (int iq = 0; iq < 2; ++iq)                                         \
          o_acc[id][iq] = __builtin_amdgcn_mfma_f32_16x16x32_bf16(             \
              vf[id], pf[iq], o_acc[id][iq], 0, 0, 0);                         \
    }                                                                          \
  }

__global__ __launch_bounds__(256, 3)
void attn(const unsigned short* __restrict__ Qbuf,
          const unsigned short* __restrict__ Kbuf,
          const unsigned short* __restrict__ Vtbuf,
          const float* __restrict__ masks,   // mask * log2e, fp32
          unsigned short* __restrict__ vals) {
  const int blk = blockIdx.x;
  const int xcd = blk & 7, slot = blk >> 3;       // slot 0..127
  const int qt = xcd * 2 + (slot >> 6);           // 2 qt values per XCD
  const int hb = slot & 63;
  const int b = hb >> 4, h = hb & 15;
  const int tid = threadIdx.x, lane = tid & 63, w = tid >> 6;
  const int lrow = lane & 15, quad = lane >> 4;
  const int sw = lrow & 7;

  __shared__ __align__(16) unsigned short Ks[2][64 * 64];  // [key][d] swizzled, dbuf
  __shared__ __align__(16) unsigned short Vs[2][64 * 64];  // [d][key] swizzled, dbuf
  __shared__ __align__(16) unsigned short Ps[128 * 64];    // Q staging, then P (swizzled)

  const unsigned short* qp = Qbuf + ((size_t)(b * 16 + h) * 2048 + qt * 128) * 64;
  const unsigned short* kp = Kbuf + (size_t)(b * 16 + h) * 2048 * 64;
  const unsigned short* vp = Vtbuf + (size_t)(b * 16 + h) * 64 * 2048;
  const float* mp = masks + (size_t)(qt * 128 + w * 32) * 2048;

  // ---- prologue: stage Q (swizzled), K0, V0, mask(0) ----
  #pragma unroll
  for (int i = 0; i < 4; ++i) {
    int e = i * 256 + tid;
    int row = e >> 3, gs = (e & 7) ^ (row & 7);
    gld_lds16(qp + (size_t)row * 64 + gs * 8, &Ps[e * 8]);
  }
  #pragma unroll
  for (int i = 0; i < 2; ++i) {  // K tile 0
    int e = i * 256 + tid;
    int row = e >> 3, gs = (e & 7) ^ (row & 7);
    gld_lds16(kp + (size_t)row * 64 + gs * 8, &Ks[0][e * 8]);
  }
  #pragma unroll
  for (int i = 0; i < 2; ++i) {  // V^T tile 0
    int e = i * 256 + tid;
    int row = e >> 3, gs = (e & 7) ^ (row & 7);
    gld_lds16(vp + (size_t)row * 2048 + gs * 8, &Vs[0][e * 8]);
  }
  f32x4 zm0[4][2], zm1[4][2];  // mask frags (double-buffered across tiles)
  #pragma unroll
  for (int iq = 0; iq < 2; ++iq) {
    const float* mrow = mp + (size_t)(iq * 16 + lrow) * 2048 + quad * 4;
    zm0[0][iq] = *(const f32x4*)(mrow);
    zm0[1][iq] = *(const f32x4*)(mrow + 16);
    zm0[2][iq] = *(const f32x4*)(mrow + 32);
    zm0[3][iq] = *(const f32x4*)(mrow + 48);
  }
  SWAIT("vmcnt(0)");
  wgbar();  // publish Q, K0, V0

  bf16x8 qf[2][2];  // [iq][ks]  B-operand: n=q, k=d
  #pragma unroll
  for (int iq = 0; iq < 2; ++iq)
    #pragma unroll
    for (int ks = 0; ks < 2; ++ks)
      qf[iq][ks] = *(const bf16x8*)&Ps[(w * 32 + iq * 16 + lrow) * 64 + ((ks * 4 + quad) ^ sw) * 8];
  // Ps reuse for P is wave-private (wave w reads/writes rows [w*32, w*32+32) only).

  f32x4 o_acc[4][2];  // O^T: d = id*16+quad*4+r, q = iq*16+lrow
  #pragma unroll
  for (int id = 0; id < 4; ++id)
    #pragma unroll
    for (int iq = 0; iq < 2; ++iq)
      #pragma unroll
      for (int r = 0; r < 4; ++r) o_acc[id][iq][r] = 0.f;
  float lsum[2] = {0.f, 0.f};

  for (int t2 = 0; t2 < 16; ++t2) {
    ATTN_TILE(2 * t2,     zm0, zm1);
    ATTN_TILE(2 * t2 + 1, zm1, zm0);
  }

  // normalize + store O^T
  unsigned short* ob = vals + (size_t)(b * 2048 + qt * 128 + w * 32) * 1024 + h * 64;
  #pragma unroll
  for (int iq = 0; iq < 2; ++iq) {
    float s = lsum[iq];
    s += __shfl_xor(s, 16);
    s += __shfl_xor(s, 32);
    float inv = 1.f / s;
    #pragma unroll
    for (int id = 0; id < 4; ++id) {
      uint2 p;
      p.x = pk_bf16(o_acc[id][iq][0] * inv, o_acc[id][iq][1] * inv);
      p.y = pk_bf16(o_acc[id][iq][2] * inv, o_acc[id][iq][3] * inv);
      *(uint2*)&ob[(size_t)(iq * 16 + lrow) * 1024 + id * 16 + quad * 4] = p;
    }
  }
}

extern "C" void kernel_launch(void* const* d_in, const int* in_sizes, int n_in,
                              void* d_out, int out_size, void* d_ws, size_t ws_size,
                              hipStream_t stream) {
  const float* x    = (const float*)d_in[0];
  const float* y    = (const float*)d_in[1];
  const float* mask = (const float*)d_in[2];
  const float* Wkv  = (const float*)d_in[3];
  const float* bkv  = (const float*)d_in[4];
  const float* Wq   = (const float*)d_in[5];
  const float* bq   = (const float*)d_in[6];
  const float* Wo   = (const float*)d_in[7];
  const float* bo   = (const float*)d_in[8];

  char* ws = (char*)d_ws;
  unsigned short* xb    = (unsigned short*)(ws + ((size_t)0 << 20));
  unsigned short* yb    = (unsigned short*)(ws + ((size_t)16 << 20));
  unsigned short* wkvt  = (unsigned short*)(ws + ((size_t)32 << 20));
  unsigned short* wqt   = (unsigned short*)(ws + ((size_t)36 << 20));
  unsigned short* wot   = (unsigned short*)(ws + ((size_t)38 << 20));
  unsigned short* kbuf  = (unsigned short*)(ws + ((size_t)40 << 20));
  unsigned short* vtbuf = (unsigned short*)(ws + ((size_t)56 << 20));
  unsigned short* qbuf  = (unsigned short*)(ws + ((size_t)72 << 20));
  unsigned short* valsb = (unsigned short*)(ws + ((size_t)88 << 20));
  float*          masks = (float*)        (ws + ((size_t)108 << 20));

  cast_xy<<<16384, 256, 0, stream>>>(x, y, xb, yb);
  scale_mask<<<4096, 256, 0, stream>>>(mask, masks);
  transpose_cast_all<<<4096, 256, 0, stream>>>(Wkv, Wq, Wo, wkvt, wqt, wot);

  // kv = x @ Wkv + bkv -> K[b,h,s,64], Vt[b,h,64,s]
  gemm128<1><<<dim3(16, 64), 256, 0, stream>>>(xb, wkvt, bkv, kbuf, vtbuf, 8192, 2048, 1024);
  // q = y @ Wq + bq -> Q[b,h,s,64] (pre-scaled)
  gemm128<2><<<dim3(8, 64), 256, 0, stream>>>(yb, wqt, bq, qbuf, nullptr, 8192, 1024, 1024);
  // attention -> vals [b,s,1024] bf16
  attn<<<1024, 256, 0, stream>>>(qbuf, kbuf, vtbuf, masks, valsb);
  // out = vals @ Wo + bo (fp32)
  gemm128<0><<<dim3(8, 64), 256, 0, stream>>>(valsb, wot, bo, (float*)d_out, nullptr, 8192, 1024, 1024);
}